// Round 14
// baseline (1052.972 us; speedup 1.0000x reference)
//
#include <hip/hip_runtime.h>
#include <hip/hip_bf16.h>
#include <hip/hip_cooperative_groups.h>

namespace cg = cooperative_groups;

using bf16x8 = __attribute__((ext_vector_type(8))) short;
using f32x4  = __attribute__((ext_vector_type(4))) float;

#define FS_CHUNK 4096

// ---------- helpers ----------
__device__ __forceinline__ float ldf(const void* p, size_t i, float isf){
  if (isf > 0.5f) return ((const float*)p)[i];
  unsigned int u = ((unsigned int)((const unsigned short*)p)[i]) << 16;
  return __uint_as_float(u);
}
__device__ __forceinline__ unsigned short f2bf(float v){
  unsigned int u = __float_as_uint(v);
  u = (u + 0x7FFFu + ((u >> 16) & 1u)) >> 16;   // RNE
  return (unsigned short)u;
}
__device__ __forceinline__ unsigned int pk2(float a, float b){
  return (unsigned int)f2bf(a) | ((unsigned int)f2bf(b) << 16);
}
__device__ __forceinline__ float lo16(unsigned int u){ return __uint_as_float(u << 16); }
__device__ __forceinline__ float hi16(unsigned int u){ return __uint_as_float(u & 0xFFFF0000u); }

__global__ void k_fill(unsigned short* o, unsigned short v, int n){
  int i = blockIdx.x*blockDim.x + threadIdx.x;
  if (i < n) o[i] = v;
}

// ---------- shared-memory union for the mega kernel ----------
struct SLin1 { unsigned short Xs[64][40]; unsigned short Wt[96][40]; };
struct SLinm { float sa[96]; float sc[96]; unsigned short Ys[64][104]; unsigned short Wt[96][104]; };
struct SAgg  { float ls[16][97]; float lq[16][97]; };
union __align__(16) SMem { SLin1 l1; SLinm lm; SAgg ag; };

struct KParams {
  const int* ei;
  const void* x;
  const void *W1, *W2, *W3, *W4;
  const void *g1, *be1, *g2, *be2, *g3, *be3, *b4;
  float* flag; float* stAll; float* W4f;
  unsigned short *Wt1, *Wt2, *Wt3;
  int *cnt, *cursor, *rowst;
  void* csrv;
  float *dinv, *hs2;
  unsigned short *HS, *Zb;
  void* out;
  long long E;
  int n, nelemX, gF8, gL, gA, gN;
  float invN;
};

#define ACC8(v) { a0+=lo16((v).x); a1+=hi16((v).x); a2+=lo16((v).y); a3+=hi16((v).y); \
                  a4+=lo16((v).z); a5+=hi16((v).z); a6+=lo16((v).w); a7+=hi16((v).w); }

// agg + fused stats, one layer (t<192 active for gather)
template<typename IT>
__device__ void agg_stage(const KParams& p, SMem& sm, const IT* csr, float* stout, int t, int nbk){
  const uint4* hsr = (const uint4*)p.HS;
  uint4* zb4 = (uint4*)p.Zb;
  int g = t % 12, ty = t / 12;
  for (int va = blockIdx.x; va < p.gA; va += nbk){
    float r[8];
    if (t < 192){
      int node = va*16 + ty;
      if (node < p.n){
        uint4 v = hsr[(size_t)node*12 + g];
        float a0 = lo16(v.x), a1 = hi16(v.x), a2 = lo16(v.y), a3 = hi16(v.y);
        float a4 = lo16(v.z), a5 = hi16(v.z), a6 = lo16(v.w), a7 = hi16(v.w);
        int b = p.rowst[node], e = b + p.cnt[node];
        int j = b;
        for (; j + 7 < e; j += 8){
          uint4 v0 = hsr[(size_t)csr[j]  *12 + g];
          uint4 v1 = hsr[(size_t)csr[j+1]*12 + g];
          uint4 v2 = hsr[(size_t)csr[j+2]*12 + g];
          uint4 v3 = hsr[(size_t)csr[j+3]*12 + g];
          uint4 v4 = hsr[(size_t)csr[j+4]*12 + g];
          uint4 v5 = hsr[(size_t)csr[j+5]*12 + g];
          uint4 v6 = hsr[(size_t)csr[j+6]*12 + g];
          uint4 v7 = hsr[(size_t)csr[j+7]*12 + g];
          ACC8(v0); ACC8(v1); ACC8(v2); ACC8(v3);
          ACC8(v4); ACC8(v5); ACC8(v6); ACC8(v7);
        }
        for (; j + 3 < e; j += 4){
          uint4 v0 = hsr[(size_t)csr[j]  *12 + g];
          uint4 v1 = hsr[(size_t)csr[j+1]*12 + g];
          uint4 v2 = hsr[(size_t)csr[j+2]*12 + g];
          uint4 v3 = hsr[(size_t)csr[j+3]*12 + g];
          ACC8(v0); ACC8(v1); ACC8(v2); ACC8(v3);
        }
        for (; j < e; ++j){
          uint4 vv = hsr[(size_t)csr[j]*12 + g];
          ACC8(vv);
        }
        float di = p.dinv[node];
        uint4 o;
        o.x = pk2(a0*di, a1*di);
        o.y = pk2(a2*di, a3*di);
        o.z = pk2(a4*di, a5*di);
        o.w = pk2(a6*di, a7*di);
        zb4[(size_t)node*12 + g] = o;
        r[0]=lo16(o.x); r[1]=hi16(o.x); r[2]=lo16(o.y); r[3]=hi16(o.y);
        r[4]=lo16(o.z); r[5]=hi16(o.z); r[6]=lo16(o.w); r[7]=hi16(o.w);
      } else {
        #pragma unroll
        for (int jj = 0; jj < 8; ++jj) r[jj] = 0.f;
      }
      #pragma unroll
      for (int jj = 0; jj < 8; ++jj){
        sm.ag.ls[ty][8*g + jj] = r[jj];
        sm.ag.lq[ty][8*g + jj] = r[jj]*r[jj];
      }
    }
    __syncthreads();
    if (t < 96){
      float s = 0.f, q = 0.f;
      #pragma unroll
      for (int rr = 0; rr < 16; ++rr){ s += sm.ag.ls[rr][t]; q += sm.ag.lq[rr][t]; }
      int rep = va & 7;
      atomicAdd(&stout[192*rep + t],      s);
      atomicAdd(&stout[192*rep + 96 + t], q);
    }
    __syncthreads();
  }
}

// BN+ReLU+MFMA GEMM, one mid layer. W staged once per stage.
__device__ void linm_stage(const KParams& p, SMem& sm, const unsigned short* Wtb,
                           const float* st, const void* gam, const void* bet,
                           int t, int nbk, float isf){
  if (t < 96){
    float ssum = 0.f, qsum = 0.f;
    #pragma unroll
    for (int r = 0; r < 8; ++r){ ssum += st[192*r + t]; qsum += st[192*r + 96 + t]; }
    float mu  = ssum*p.invN;
    float var = fmaxf(qsum*p.invN - mu*mu, 0.f);
    float istd = rsqrtf(var + 1e-5f);
    float a = ldf(gam, t, isf)*istd;
    sm.lm.sa[t] = a; sm.lm.sc[t] = ldf(bet, t, isf) - mu*a;
  }
  for (int q = t; q < 1152; q += 256){
    uint4 v = ((const uint4*)Wtb)[q];
    *(uint4*)&sm.lm.Wt[q/12][8*(q - 12*(q/12))] = v;
  }
  __syncthreads();
  int lane = t & 63, wv = t >> 6;
  for (int vb = blockIdx.x; vb < p.gL; vb += nbk){
    {
      int row = t >> 2, part = t & 3;
      int node = vb*64 + row;
      if (node < p.n){
        const uint4* zr = (const uint4*)(p.Zb + (size_t)96*node) + 3*part;
        #pragma unroll
        for (int q = 0; q < 3; ++q){
          uint4 zz = zr[q];
          int k = 24*part + 8*q;
          float y0 = fmaxf(lo16(zz.x)*sm.lm.sa[k]   + sm.lm.sc[k],   0.f);
          float y1 = fmaxf(hi16(zz.x)*sm.lm.sa[k+1] + sm.lm.sc[k+1], 0.f);
          float y2 = fmaxf(lo16(zz.y)*sm.lm.sa[k+2] + sm.lm.sc[k+2], 0.f);
          float y3 = fmaxf(hi16(zz.y)*sm.lm.sa[k+3] + sm.lm.sc[k+3], 0.f);
          float y4 = fmaxf(lo16(zz.z)*sm.lm.sa[k+4] + sm.lm.sc[k+4], 0.f);
          float y5 = fmaxf(hi16(zz.z)*sm.lm.sa[k+5] + sm.lm.sc[k+5], 0.f);
          float y6 = fmaxf(lo16(zz.w)*sm.lm.sa[k+6] + sm.lm.sc[k+6], 0.f);
          float y7 = fmaxf(hi16(zz.w)*sm.lm.sa[k+7] + sm.lm.sc[k+7], 0.f);
          *(unsigned int*)&sm.lm.Ys[row][k]     = pk2(y0, y1);
          *(unsigned int*)&sm.lm.Ys[row][k + 2] = pk2(y2, y3);
          *(unsigned int*)&sm.lm.Ys[row][k + 4] = pk2(y4, y5);
          *(unsigned int*)&sm.lm.Ys[row][k + 6] = pk2(y6, y7);
        }
      } else {
        unsigned int* yp = (unsigned int*)&sm.lm.Ys[row][24*part];
        #pragma unroll
        for (int q = 0; q < 12; ++q) yp[q] = 0u;
      }
    }
    __syncthreads();
    int m = lane & 15, quad = lane >> 4;
    bf16x8 av[3];
    #pragma unroll
    for (int kt = 0; kt < 3; ++kt)
      av[kt] = *(const bf16x8*)&sm.lm.Ys[16*wv + m][32*kt + 8*quad];
    f32x4 acc[6];
    #pragma unroll
    for (int c = 0; c < 6; ++c) acc[c] = (f32x4)(0.f);
    #pragma unroll
    for (int c = 0; c < 6; ++c){
      const unsigned short* wrow = &sm.lm.Wt[16*c + m][8*quad];
      #pragma unroll
      for (int kt = 0; kt < 3; ++kt){
        bf16x8 bv = *(const bf16x8*)(wrow + 32*kt);
        acc[c] = __builtin_amdgcn_mfma_f32_16x16x32_bf16(av[kt], bv, acc[c], 0, 0, 0);
      }
    }
    int rowbase = vb*64 + 16*wv + 4*quad;
    float div[4];
    #pragma unroll
    for (int r = 0; r < 4; ++r){ int rr = rowbase + r; div[r] = (rr < p.n) ? p.dinv[rr] : 0.f; }
    #pragma unroll
    for (int c = 0; c < 6; ++c){
      int col = 16*c + m;
      #pragma unroll
      for (int r = 0; r < 4; ++r){
        int rr = rowbase + r;
        if (rr < p.n) p.HS[(size_t)96*rr + col] = f2bf(acc[c][r]*div[r]);
      }
    }
    __syncthreads();
  }
}

// ================== THE MEGA KERNEL (cooperative) ==================
template<typename IT>
__global__ __launch_bounds__(256) void k_mega(KParams p){
  cg::grid_group grid = cg::this_grid();
  __shared__ SMem sm;
  __shared__ int sflags[2];
  const int t = threadIdx.x;
  const int nbk = (int)gridDim.x;
  const int lane = t & 63, wv = t >> 6;
  IT* csr = (IT*)p.csrv;
  int* gctr = (int*)(p.stAll + 4608);
  float* stA = p.stAll;
  float* stB = p.stAll + 1536;
  float* stC = p.stAll + 3072;

  // ---- S0: block 0 detect+weights; others zero cnt/st/gctr ----
  if (blockIdx.x == 0){
    if (t == 0){ sflags[0] = 0; sflags[1] = 1; }
    __syncthreads();
    {
      int i = 2*t;
      if (i < p.nelemX){
        unsigned e8 = (((const unsigned short*)p.x)[i] >> 7) & 0xFFu;
        if (e8 >= 140u) sflags[0] = 1;
      }
      if ((long long)(2*t+1) < 2*p.E){
        if (((const unsigned int*)p.ei)[2*t+1] != 0u) sflags[1] = 0;
      }
    }
    __syncthreads();
    if (t == 0){ p.flag[0] = (float)sflags[0]; p.flag[1] = (float)sflags[1]; }
    float isf0 = (float)sflags[0];
    for (int q = t; q < 3072; q += 256){
      int nn = q >> 5, k = q & 31;
      p.Wt1[q] = f2bf(ldf(p.W1, (size_t)96*k + nn, isf0));
    }
    for (int q = t; q < 9216; q += 256){
      int nn = q/96, k = q - 96*nn;
      p.Wt2[q] = f2bf(ldf(p.W2, (size_t)96*k + nn, isf0));
      p.Wt3[q] = f2bf(ldf(p.W3, (size_t)96*k + nn, isf0));
    }
    if (t < 192) p.W4f[t] = ldf(p.W4, t, isf0);
  } else {
    int total = p.n + 4609;
    for (int i = (int)(blockIdx.x-1)*256 + t; i < total; i += (nbk-1)*256){
      if (i < p.n) p.cnt[i] = 0; else p.stAll[i - p.n] = 0.f;
    }
  }
  __threadfence();
  grid.sync();

  const bool i64 = p.flag[1] > 0.5f;
  const float isf = p.flag[0];

  // ---- S1: degree count ----
  for (long long i = (long long)blockIdx.x*256 + t; i < p.E; i += (long long)nbk*256){
    int d = i64 ? p.ei[2*p.E + 2*i] : p.ei[p.E + i];
    if ((unsigned)d < (unsigned)p.n) atomicAdd(&p.cnt[d], 1);
  }
  __threadfence();
  grid.sync();

  // ---- S2: unordered row allocation ----
  {
    int chunks = (p.n + 255) >> 8;
    for (int c = blockIdx.x; c < chunks; c += nbk){
      int i = c*256 + t;
      int v = (i < p.n) ? p.cnt[i] : 0;
      int s = v;
      #pragma unroll
      for (int off = 1; off < 64; off <<= 1){
        int u = __shfl_up(s, off, 64);
        if (lane >= off) s += u;
      }
      int wtot = __shfl(s, 63, 64);
      int base = 0;
      if (lane == 63) base = atomicAdd(gctr, wtot);
      base = __shfl(base, 63, 64);
      if (i < p.n){
        int r = base + s - v;
        p.rowst[i]  = r;
        p.cursor[i] = r;
        p.dinv[i]   = rsqrtf((float)(1 + v));
      }
    }
  }
  __threadfence();
  grid.sync();

  // ---- S3: CSR fill (vb<gF8) + MFMA layer1 (rest); Wt1 staged once ----
  for (int q = t; q < 384; q += 256){
    uint4 v = ((const uint4*)p.Wt1)[q];
    *(uint4*)&sm.l1.Wt[q >> 2][(q & 3)*8] = v;
  }
  __syncthreads();
  for (int vb = blockIdx.x; vb < p.gF8 + p.gL; vb += nbk){
    if (vb < p.gF8){
      int part = vb & 7;
      long long base = (long long)(vb >> 3) * FS_CHUNK;
      int pl = (int)(((long long)p.n *  part     ) >> 3);
      int pr = (int)(((long long)p.n * (part + 1)) >> 3);
      long long lim = base + FS_CHUNK < p.E ? base + FS_CHUNK : p.E;
      for (long long i = base + t; i < lim; i += 256){
        int s, d;
        if (i64){ s = p.ei[2*i]; d = p.ei[2*p.E + 2*i]; }
        else    { s = p.ei[i];   d = p.ei[p.E + i];     }
        if (d >= pl && d < pr && (unsigned)s < (unsigned)p.n){
          int pp = atomicAdd(&p.cursor[d], 1);
          csr[pp] = (IT)s;
        }
      }
    } else {
      int bid = vb - p.gF8;
      {
        int row = t >> 2, part4 = t & 3;
        int node = bid*64 + row;
        uint4 o;
        if (node < p.n){
          if (isf > 0.5f){
            const float* xr = (const float*)p.x + (size_t)32*node + 8*part4;
            o.x = pk2(xr[0], xr[1]); o.y = pk2(xr[2], xr[3]);
            o.z = pk2(xr[4], xr[5]); o.w = pk2(xr[6], xr[7]);
          } else {
            o = ((const uint4*)p.x)[(size_t)4*node + part4];
          }
        } else { o.x = o.y = o.z = o.w = 0u; }
        *(uint4*)&sm.l1.Xs[row][8*part4] = o;
      }
      __syncthreads();
      int m = lane & 15, quad = lane >> 4;
      bf16x8 av = *(const bf16x8*)&sm.l1.Xs[16*wv + m][8*quad];
      f32x4 acc[6];
      #pragma unroll
      for (int c = 0; c < 6; ++c) acc[c] = (f32x4)(0.f);
      #pragma unroll
      for (int c = 0; c < 6; ++c){
        bf16x8 bv = *(const bf16x8*)&sm.l1.Wt[16*c + m][8*quad];
        acc[c] = __builtin_amdgcn_mfma_f32_16x16x32_bf16(av, bv, acc[c], 0, 0, 0);
      }
      int rowbase = bid*64 + 16*wv + 4*quad;
      float div[4];
      #pragma unroll
      for (int r = 0; r < 4; ++r){ int rr = rowbase + r; div[r] = (rr < p.n) ? p.dinv[rr] : 0.f; }
      #pragma unroll
      for (int c = 0; c < 6; ++c){
        int col = 16*c + m;
        #pragma unroll
        for (int r = 0; r < 4; ++r){
          int rr = rowbase + r;
          if (rr < p.n) p.HS[(size_t)96*rr + col] = f2bf(acc[c][r]*div[r]);
        }
      }
      __syncthreads();
    }
  }
  __threadfence();
  grid.sync();

  // ---- S4..S8: [agg+stats -> linm] x2, agg ----
  agg_stage<IT>(p, sm, csr, stA, t, nbk);
  __threadfence(); grid.sync();
  linm_stage(p, sm, p.Wt2, stA, p.g1, p.be1, t, nbk, isf);
  __threadfence(); grid.sync();
  agg_stage<IT>(p, sm, csr, stB, t, nbk);
  __threadfence(); grid.sync();
  linm_stage(p, sm, p.Wt3, stB, p.g2, p.be2, t, nbk, isf);
  __threadfence(); grid.sync();
  agg_stage<IT>(p, sm, csr, stC, t, nbk);
  __threadfence(); grid.sync();

  // ---- S9: layer 4 (96->2, VALU) ----
  if (t < 96){
    float ssum = 0.f, qsum = 0.f;
    #pragma unroll
    for (int r = 0; r < 8; ++r){ ssum += stC[192*r + t]; qsum += stC[192*r + 96 + t]; }
    float mu  = ssum*p.invN;
    float var = fmaxf(qsum*p.invN - mu*mu, 0.f);
    float istd = rsqrtf(var + 1e-5f);
    float a = ldf(p.g3, t, isf)*istd;
    sm.lm.sa[t] = a; sm.lm.sc[t] = ldf(p.be3, t, isf) - mu*a;
  }
  __syncthreads();
  for (int vb = blockIdx.x; vb < p.gN; vb += nbk){
    int i = vb*256 + t;
    if (i < p.n){
      const uint4* zr = (const uint4*)(p.Zb + (size_t)96*i);
      float a0 = 0.f, a1 = 0.f;
      #pragma unroll
      for (int q = 0; q < 12; ++q){
        uint4 zz = zr[q];
        int k = 8*q;
        const float* Wf = p.W4f;
        float y;
        y = fmaxf(lo16(zz.x)*sm.lm.sa[k]   + sm.lm.sc[k],   0.f); a0 += y*Wf[2*k];    a1 += y*Wf[2*k+1];
        y = fmaxf(hi16(zz.x)*sm.lm.sa[k+1] + sm.lm.sc[k+1], 0.f); a0 += y*Wf[2*k+2];  a1 += y*Wf[2*k+3];
        y = fmaxf(lo16(zz.y)*sm.lm.sa[k+2] + sm.lm.sc[k+2], 0.f); a0 += y*Wf[2*k+4];  a1 += y*Wf[2*k+5];
        y = fmaxf(hi16(zz.y)*sm.lm.sa[k+3] + sm.lm.sc[k+3], 0.f); a0 += y*Wf[2*k+6];  a1 += y*Wf[2*k+7];
        y = fmaxf(lo16(zz.z)*sm.lm.sa[k+4] + sm.lm.sc[k+4], 0.f); a0 += y*Wf[2*k+8];  a1 += y*Wf[2*k+9];
        y = fmaxf(hi16(zz.z)*sm.lm.sa[k+5] + sm.lm.sc[k+5], 0.f); a0 += y*Wf[2*k+10]; a1 += y*Wf[2*k+11];
        y = fmaxf(lo16(zz.w)*sm.lm.sa[k+6] + sm.lm.sc[k+6], 0.f); a0 += y*Wf[2*k+12]; a1 += y*Wf[2*k+13];
        y = fmaxf(hi16(zz.w)*sm.lm.sa[k+7] + sm.lm.sc[k+7], 0.f); a0 += y*Wf[2*k+14]; a1 += y*Wf[2*k+15];
      }
      float di = p.dinv[i];
      p.hs2[(size_t)2*i]   = di*a0;
      p.hs2[(size_t)2*i+1] = di*a1;
    }
  }
  __threadfence();
  grid.sync();

  // ---- S10: output aggregation ----
  for (int vb = blockIdx.x; vb < p.gN; vb += nbk){
    int node = vb*256 + t;
    if (node < p.n){
      const float2* hs2 = (const float2*)p.hs2;
      float2 a = hs2[node];
      int b = p.rowst[node], e = b + p.cnt[node];
      for (int j = b; j < e; ++j){
        float2 v = hs2[(size_t)csr[j]];
        a.x += v.x; a.y += v.y;
      }
      float di = p.dinv[node];
      float v0 = a.x*di + ldf(p.b4, 0, isf);
      float v1 = a.y*di + ldf(p.b4, 1, isf);
      if (isf > 0.5f){
        ((float*)p.out)[(size_t)2*node]   = v0;
        ((float*)p.out)[(size_t)2*node+1] = v1;
      } else {
        ((unsigned short*)p.out)[(size_t)2*node]   = f2bf(v0);
        ((unsigned short*)p.out)[(size_t)2*node+1] = f2bf(v1);
      }
    }
  }
}

// ================== FALLBACK (round-13 proven path) ==================
__global__ void k_prep(const unsigned short* xh, const unsigned int* eu,
                       float* flag, int nelemX, long long E,
                       const void* W1, const void* W2, const void* W3, const void* W4,
                       unsigned short* __restrict__ Wt1, unsigned short* __restrict__ Wt2,
                       unsigned short* __restrict__ Wt3, float* __restrict__ W4f,
                       int* __restrict__ cnt, float* __restrict__ stAll, int n){
  int t = threadIdx.x;
  if (blockIdx.x > 0){
    int total = n + 4609;
    for (int i = (int)(blockIdx.x-1)*256 + t; i < total; i += (int)(gridDim.x-1)*256){
      if (i < n) cnt[i] = 0; else stAll[i - n] = 0.f;
    }
    return;
  }
  __shared__ int sf32, si64;
  __shared__ float sisf;
  if (t == 0){ sf32 = 0; si64 = 1; }
  __syncthreads();
  {
    int i = 2*t;
    if (i < nelemX){
      unsigned e8 = (xh[i] >> 7) & 0xFFu;
      if (e8 >= 140u) sf32 = 1;
    }
    if ((long long)(2*t + 1) < 2*E){
      if (eu[2*t + 1] != 0u) si64 = 0;
    }
  }
  __syncthreads();
  if (t == 0){ flag[0] = (float)sf32; flag[1] = (float)si64; sisf = (float)sf32; }
  __syncthreads();
  float isf = sisf;
  for (int q = t; q < 3072; q += 256){
    int nn = q >> 5, k = q & 31;
    Wt1[q] = f2bf(ldf(W1, (size_t)96*k + nn, isf));
  }
  for (int q = t; q < 9216; q += 256){
    int nn = q/96, k = q - 96*nn;
    Wt2[q] = f2bf(ldf(W2, (size_t)96*k + nn, isf));
    Wt3[q] = f2bf(ldf(W3, (size_t)96*k + nn, isf));
  }
  if (t < 192) W4f[t] = ldf(W4, t, isf);
}

__global__ void k_cnt(const int* __restrict__ ei, const float* __restrict__ flag,
                      int* __restrict__ cnt, long long E, int n){
  long long i = (long long)blockIdx.x*blockDim.x + threadIdx.x;
  if (i >= E) return;
  int d = (flag[1] > 0.5f) ? ei[2*E + 2*i] : ei[E + i];
  if ((unsigned)d < (unsigned)n) atomicAdd(&cnt[d], 1);
}

__global__ void k_emit2(const int* __restrict__ cnt, int* __restrict__ gctr,
                        int* __restrict__ rowst, int* __restrict__ cursor,
                        float* __restrict__ dinv, int n){
  int i = blockIdx.x*256 + threadIdx.x;
  int lane = threadIdx.x & 63;
  int v = (i < n) ? cnt[i] : 0;
  int s = v;
  #pragma unroll
  for (int off = 1; off < 64; off <<= 1){
    int u = __shfl_up(s, off, 64);
    if (lane >= off) s += u;
  }
  int wtot = __shfl(s, 63, 64);
  int base = 0;
  if (lane == 63) base = atomicAdd(gctr, wtot);
  base = __shfl(base, 63, 64);
  if (i < n){
    int r = base + s - v;
    rowst[i]  = r;
    cursor[i] = r;
    dinv[i]   = rsqrtf((float)(1 + v));
  }
}

template<typename IT>
__global__ __launch_bounds__(256) void k_fl1(const int* __restrict__ ei,
      const float* __restrict__ flag, int* __restrict__ cursor, IT* __restrict__ csr,
      long long E, int n, int gF8,
      const void* __restrict__ x, const unsigned short* __restrict__ Wt1b,
      const float* __restrict__ dinv, unsigned short* __restrict__ HS){
  __shared__ __align__(16) unsigned short Xs[64][40];
  __shared__ __align__(16) unsigned short Wt[96][40];
  int t = threadIdx.x;
  if ((int)blockIdx.x < gF8){
    int part = blockIdx.x & 7;
    long long base = (long long)(blockIdx.x >> 3) * FS_CHUNK;
    int pl = (int)(((long long)n *  part     ) >> 3);
    int pr = (int)(((long long)n * (part + 1)) >> 3);
    bool i64 = (flag[1] > 0.5f);
    long long lim = base + FS_CHUNK < E ? base + FS_CHUNK : E;
    for (long long i = base + t; i < lim; i += 256){
      int s, d;
      if (i64){ s = ei[2*i]; d = ei[2*E + 2*i]; }
      else    { s = ei[i];   d = ei[E + i];     }
      if (d >= pl && d < pr && (unsigned)s < (unsigned)n){
        int p = atomicAdd(&cursor[d], 1);
        csr[p] = (IT)s;
      }
    }
    return;
  }
  int bid = blockIdx.x - gF8;
  float isf = flag[0];
  for (int q = t; q < 384; q += 256){
    uint4 v = ((const uint4*)Wt1b)[q];
    *(uint4*)&Wt[q >> 2][(q & 3)*8] = v;
  }
  {
    int row = t >> 2, part = t & 3;
    int node = bid*64 + row;
    uint4 o;
    if (node < n){
      if (isf > 0.5f){
        const float* xr = (const float*)x + (size_t)32*node + 8*part;
        o.x = pk2(xr[0], xr[1]); o.y = pk2(xr[2], xr[3]);
        o.z = pk2(xr[4], xr[5]); o.w = pk2(xr[6], xr[7]);
      } else {
        o = ((const uint4*)x)[(size_t)4*node + part];
      }
    } else { o.x = o.y = o.z = o.w = 0u; }
    *(uint4*)&Xs[row][8*part] = o;
  }
  __syncthreads();
  int wv = t >> 6, lane = t & 63;
  int m = lane & 15, quad = lane >> 4;
  bf16x8 av = *(const bf16x8*)&Xs[16*wv + m][8*quad];
  f32x4 acc[6];
  #pragma unroll
  for (int c = 0; c < 6; ++c) acc[c] = (f32x4)(0.f);
  #pragma unroll
  for (int c = 0; c < 6; ++c){
    bf16x8 bv = *(const bf16x8*)&Wt[16*c + m][8*quad];
    acc[c] = __builtin_amdgcn_mfma_f32_16x16x32_bf16(av, bv, acc[c], 0, 0, 0);
  }
  int rowbase = bid*64 + 16*wv + 4*quad;
  float div[4];
  #pragma unroll
  for (int r = 0; r < 4; ++r){ int rr = rowbase + r; div[r] = (rr < n) ? dinv[rr] : 0.f; }
  #pragma unroll
  for (int c = 0; c < 6; ++c){
    int col = 16*c + m;
    #pragma unroll
    for (int r = 0; r < 4; ++r){
      int rr = rowbase + r;
      if (rr < n) HS[(size_t)96*rr + col] = f2bf(acc[c][r]*div[r]);
    }
  }
}

template<typename IT>
__global__ __launch_bounds__(192) void k_agg(const uint4* __restrict__ hsr,
      const int* __restrict__ rowst, const int* __restrict__ cnt,
      const IT* __restrict__ csr,
      const float* __restrict__ dinv, uint4* __restrict__ zb4,
      float* __restrict__ stout, int n){
  __shared__ float ls[16][97], lq[16][97];
  int g = threadIdx.x, ty = threadIdx.y;
  int t = ty*12 + g;
  int node = blockIdx.x*16 + ty;
  float r[8];
  if (node < n){
    uint4 v = hsr[(size_t)node*12 + g];
    float a0 = lo16(v.x), a1 = hi16(v.x), a2 = lo16(v.y), a3 = hi16(v.y);
    float a4 = lo16(v.z), a5 = hi16(v.z), a6 = lo16(v.w), a7 = hi16(v.w);
    int b = rowst[node], e = b + cnt[node];
    int j = b;
    for (; j + 7 < e; j += 8){
      uint4 v0 = hsr[(size_t)csr[j]  *12 + g];
      uint4 v1 = hsr[(size_t)csr[j+1]*12 + g];
      uint4 v2 = hsr[(size_t)csr[j+2]*12 + g];
      uint4 v3 = hsr[(size_t)csr[j+3]*12 + g];
      uint4 v4 = hsr[(size_t)csr[j+4]*12 + g];
      uint4 v5 = hsr[(size_t)csr[j+5]*12 + g];
      uint4 v6 = hsr[(size_t)csr[j+6]*12 + g];
      uint4 v7 = hsr[(size_t)csr[j+7]*12 + g];
      ACC8(v0); ACC8(v1); ACC8(v2); ACC8(v3);
      ACC8(v4); ACC8(v5); ACC8(v6); ACC8(v7);
    }
    for (; j + 3 < e; j += 4){
      uint4 v0 = hsr[(size_t)csr[j]  *12 + g];
      uint4 v1 = hsr[(size_t)csr[j+1]*12 + g];
      uint4 v2 = hsr[(size_t)csr[j+2]*12 + g];
      uint4 v3 = hsr[(size_t)csr[j+3]*12 + g];
      ACC8(v0); ACC8(v1); ACC8(v2); ACC8(v3);
    }
    for (; j < e; ++j){
      uint4 vv = hsr[(size_t)csr[j]*12 + g];
      ACC8(vv);
    }
    float di = dinv[node];
    uint4 o;
    o.x = pk2(a0*di, a1*di);
    o.y = pk2(a2*di, a3*di);
    o.z = pk2(a4*di, a5*di);
    o.w = pk2(a6*di, a7*di);
    zb4[(size_t)node*12 + g] = o;
    r[0]=lo16(o.x); r[1]=hi16(o.x); r[2]=lo16(o.y); r[3]=hi16(o.y);
    r[4]=lo16(o.z); r[5]=hi16(o.z); r[6]=lo16(o.w); r[7]=hi16(o.w);
  } else {
    #pragma unroll
    for (int jj = 0; jj < 8; ++jj) r[jj] = 0.f;
  }
  #pragma unroll
  for (int jj = 0; jj < 8; ++jj){
    ls[ty][8*g + jj] = r[jj];
    lq[ty][8*g + jj] = r[jj]*r[jj];
  }
  __syncthreads();
  if (t < 96){
    float s = 0.f, q = 0.f;
    #pragma unroll
    for (int rr = 0; rr < 16; ++rr){ s += ls[rr][t]; q += lq[rr][t]; }
    int rep = blockIdx.x & 7;
    atomicAdd(&stout[192*rep + t],      s);
    atomicAdd(&stout[192*rep + 96 + t], q);
  }
}

__global__ __launch_bounds__(256) void k_linm(const unsigned short* __restrict__ zb,
      const unsigned short* __restrict__ Wtb, const float* __restrict__ st,
      const void* __restrict__ gam, const void* __restrict__ bet,
      const float* __restrict__ flag, const float* __restrict__ dinv,
      unsigned short* __restrict__ HS, int n, float invN){
  __shared__ float sa[96], sc[96];
  __shared__ __align__(16) unsigned short Ys[64][104];
  __shared__ __align__(16) unsigned short Wt[96][104];
  int t = threadIdx.x;
  if (t < 96){
    float ssum = 0.f, qsum = 0.f;
    #pragma unroll
    for (int r = 0; r < 8; ++r){ ssum += st[192*r + t]; qsum += st[192*r + 96 + t]; }
    float isf = flag[0];
    float mu  = ssum*invN;
    float var = fmaxf(qsum*invN - mu*mu, 0.f);
    float istd = rsqrtf(var + 1e-5f);
    float a = ldf(gam, t, isf)*istd;
    sa[t] = a; sc[t] = ldf(bet, t, isf) - mu*a;
  }
  for (int q = t; q < 1152; q += 256){
    uint4 v = ((const uint4*)Wtb)[q];
    *(uint4*)&Wt[q/12][8*(q - 12*(q/12))] = v;
  }
  __syncthreads();
  {
    int row = t >> 2, part = t & 3;
    int node = blockIdx.x*64 + row;
    if (node < n){
      const uint4* zr = (const uint4*)(zb + (size_t)96*node) + 3*part;
      #pragma unroll
      for (int q = 0; q < 3; ++q){
        uint4 zz = zr[q];
        int k = 24*part + 8*q;
        float y0 = fmaxf(lo16(zz.x)*sa[k]   + sc[k],   0.f);
        float y1 = fmaxf(hi16(zz.x)*sa[k+1] + sc[k+1], 0.f);
        float y2 = fmaxf(lo16(zz.y)*sa[k+2] + sc[k+2], 0.f);
        float y3 = fmaxf(hi16(zz.y)*sa[k+3] + sc[k+3], 0.f);
        float y4 = fmaxf(lo16(zz.z)*sa[k+4] + sc[k+4], 0.f);
        float y5 = fmaxf(hi16(zz.z)*sa[k+5] + sc[k+5], 0.f);
        float y6 = fmaxf(lo16(zz.w)*sa[k+6] + sc[k+6], 0.f);
        float y7 = fmaxf(hi16(zz.w)*sa[k+7] + sc[k+7], 0.f);
        *(unsigned int*)&Ys[row][k]     = pk2(y0, y1);
        *(unsigned int*)&Ys[row][k + 2] = pk2(y2, y3);
        *(unsigned int*)&Ys[row][k + 4] = pk2(y4, y5);
        *(unsigned int*)&Ys[row][k + 6] = pk2(y6, y7);
      }
    } else {
      unsigned int* yp = (unsigned int*)&Ys[row][24*part];
      #pragma unroll
      for (int q = 0; q < 12; ++q) yp[q] = 0u;
    }
  }
  __syncthreads();
  int wv = t >> 6, lane = t & 63;
  int m = lane & 15, quad = lane >> 4;
  bf16x8 av[3];
  #pragma unroll
  for (int kt = 0; kt < 3; ++kt)
    av[kt] = *(const bf16x8*)&Ys[16*wv + m][32*kt + 8*quad];
  f32x4 acc[6];
  #pragma unroll
  for (int c = 0; c < 6; ++c) acc[c] = (f32x4)(0.f);
  #pragma unroll
  for (int c = 0; c < 6; ++c){
    const unsigned short* wrow = &Wt[16*c + m][8*quad];
    #pragma unroll
    for (int kt = 0; kt < 3; ++kt){
      bf16x8 bv = *(const bf16x8*)(wrow + 32*kt);
      acc[c] = __builtin_amdgcn_mfma_f32_16x16x32_bf16(av[kt], bv, acc[c], 0, 0, 0);
    }
  }
  int rowbase = blockIdx.x*64 + 16*wv + 4*quad;
  float div[4];
  #pragma unroll
  for (int r = 0; r < 4; ++r){ int rr = rowbase + r; div[r] = (rr < n) ? dinv[rr] : 0.f; }
  #pragma unroll
  for (int c = 0; c < 6; ++c){
    int col = 16*c + m;
    #pragma unroll
    for (int r = 0; r < 4; ++r){
      int rr = rowbase + r;
      if (rr < n) HS[(size_t)96*rr + col] = f2bf(acc[c][r]*div[r]);
    }
  }
}

__global__ __launch_bounds__(256) void k_lin4(const unsigned short* __restrict__ zb,
      const float* __restrict__ Wf, const float* __restrict__ st,
      const void* __restrict__ gam, const void* __restrict__ bet,
      const float* __restrict__ flag, const float* __restrict__ dinv,
      float* __restrict__ hs2, int n, float invN){
  __shared__ float sa[96], sc[96];
  int t = threadIdx.x;
  if (t < 96){
    float ssum = 0.f, qsum = 0.f;
    #pragma unroll
    for (int r = 0; r < 8; ++r){ ssum += st[192*r + t]; qsum += st[192*r + 96 + t]; }
    float isf = flag[0];
    float mu  = ssum*invN;
    float var = fmaxf(qsum*invN - mu*mu, 0.f);
    float istd = rsqrtf(var + 1e-5f);
    float a = ldf(gam, t, isf)*istd;
    sa[t] = a; sc[t] = ldf(bet, t, isf) - mu*a;
  }
  __syncthreads();
  int i = blockIdx.x*blockDim.x + t;
  if (i >= n) return;
  const uint4* zr = (const uint4*)(zb + (size_t)96*i);
  float a0 = 0.f, a1 = 0.f;
  #pragma unroll
  for (int q = 0; q < 12; ++q){
    uint4 zz = zr[q];
    int k = 8*q;
    float y;
    y = fmaxf(lo16(zz.x)*sa[k]   + sc[k],   0.f); a0 += y*Wf[2*k];    a1 += y*Wf[2*k+1];
    y = fmaxf(hi16(zz.x)*sa[k+1] + sc[k+1], 0.f); a0 += y*Wf[2*k+2];  a1 += y*Wf[2*k+3];
    y = fmaxf(lo16(zz.y)*sa[k+2] + sc[k+2], 0.f); a0 += y*Wf[2*k+4];  a1 += y*Wf[2*k+5];
    y = fmaxf(hi16(zz.y)*sa[k+3] + sc[k+3], 0.f); a0 += y*Wf[2*k+6];  a1 += y*Wf[2*k+7];
    y = fmaxf(lo16(zz.z)*sa[k+4] + sc[k+4], 0.f); a0 += y*Wf[2*k+8];  a1 += y*Wf[2*k+9];
    y = fmaxf(hi16(zz.z)*sa[k+5] + sc[k+5], 0.f); a0 += y*Wf[2*k+10]; a1 += y*Wf[2*k+11];
    y = fmaxf(lo16(zz.w)*sa[k+6] + sc[k+6], 0.f); a0 += y*Wf[2*k+12]; a1 += y*Wf[2*k+13];
    y = fmaxf(hi16(zz.w)*sa[k+7] + sc[k+7], 0.f); a0 += y*Wf[2*k+14]; a1 += y*Wf[2*k+15];
  }
  float di = dinv[i];
  hs2[(size_t)2*i]   = di*a0;
  hs2[(size_t)2*i+1] = di*a1;
}

template<typename IT>
__global__ void k_agg2(const float2* __restrict__ hs2, const int* __restrict__ rowst,
                       const int* __restrict__ cnt, const IT* __restrict__ csr,
                       const float* __restrict__ dinv,
                       const void* __restrict__ b4, const float* __restrict__ flag,
                       void* __restrict__ out, int n){
  int node = blockIdx.x*blockDim.x + threadIdx.x;
  if (node >= n) return;
  float2 a = hs2[node];
  int b = rowst[node], e = b + cnt[node];
  for (int j = b; j < e; ++j){
    float2 v = hs2[(size_t)csr[j]];
    a.x += v.x; a.y += v.y;
  }
  float isf = flag[0];
  float di = dinv[node];
  float v0 = a.x*di + ldf(b4, 0, isf);
  float v1 = a.y*di + ldf(b4, 1, isf);
  if (isf > 0.5f){
    ((float*)out)[(size_t)2*node]   = v0;
    ((float*)out)[(size_t)2*node+1] = v1;
  } else {
    ((unsigned short*)out)[(size_t)2*node]   = f2bf(v0);
    ((unsigned short*)out)[(size_t)2*node+1] = f2bf(v1);
  }
}

extern "C" void kernel_launch(void* const* d_in, const int* in_sizes, int n_in,
                              void* d_out, int out_size, void* d_ws, size_t ws_size,
                              hipStream_t stream)
{
  const int B = 256;
  unsigned short* outh = (unsigned short*)d_out;

  if (n_in < 16){
    k_fill<<<(out_size+B-1)/B, B, 0, stream>>>(outh, 0x3F40u, out_size); return;
  }
  const int N = in_sizes[0] / 32;
  const long long E = in_sizes[1] / 2;
  if (in_sizes[0] % 32 != 0 || out_size != 2*N){
    k_fill<<<(out_size+B-1)/B, B, 0, stream>>>(outh, 0x3F60u, out_size); return;
  }
  const bool u16 = (N < 65536);

  // ---- workspace layout ----
  size_t Npad = ((size_t)N + 3) & ~(size_t)3;
  float* ws   = (float*)d_ws;
  float* dinv = ws;                               // Npad
  float* hs2  = dinv + Npad;                      // 2N
  float* flag = hs2 + (size_t)2*N;                // 4
  float* stAll= flag + 4;                         // 4608 stats + 1 gctr (+3 pad)
  float* W4f  = stAll + 4612;                     // 192
  unsigned short* Wt1b = (unsigned short*)(W4f + 192);
  unsigned short* Wt2b = Wt1b + 3072;
  unsigned short* Wt3b = Wt2b + 9216;
  int* cnt    = (int*)(Wt3b + 9216);              // N
  int* cursor = cnt + N;                          // N
  int* rowst  = cursor + N;                       // N
  void* csrv  = (void*)(rowst + N);               // E entries
  size_t csrBytes = (size_t)E * (u16 ? 2 : 4);
  uintptr_t hp_ = (uintptr_t)csrv + csrBytes;
  hp_ = (hp_ + 15) & ~(uintptr_t)15;
  unsigned short* HS = (unsigned short*)hp_;      // 96N bf16
  unsigned short* Zb = HS + (size_t)96*N;         // 96N bf16

  size_t needB = ((uintptr_t)(Zb + (size_t)96*N) - (uintptr_t)d_ws) + 64;
  if (ws_size < needB){
    k_fill<<<(out_size+B-1)/B, B, 0, stream>>>(outh, 0x3F00u, out_size); return;
  }

  const void* x  = d_in[0];
  const int*  ei = (const int*)d_in[1];
  const void* W1 = d_in[2];
  const void* g1 = d_in[4];  const void* be1 = d_in[5];
  const void* W2 = d_in[6];
  const void* g2 = d_in[8];  const void* be2 = d_in[9];
  const void* W3 = d_in[10];
  const void* g3 = d_in[12]; const void* be3 = d_in[13];
  const void* W4 = d_in[14];
  const void* b4 = d_in[15];

  int gN  = (N + B - 1)/B;
  int gE  = (int)((E + B - 1)/B);
  int nb  = (N + 255)/256;
  int gA  = (N + 15)/16;
  int gL  = (N + 63)/64;
  int gF8 = (int)((E + FS_CHUNK - 1)/FS_CHUNK) * 8;
  float invN = 1.0f / (float)N;

  KParams kp;
  kp.ei = ei; kp.x = x;
  kp.W1 = W1; kp.W2 = W2; kp.W3 = W3; kp.W4 = W4;
  kp.g1 = g1; kp.be1 = be1; kp.g2 = g2; kp.be2 = be2; kp.g3 = g3; kp.be3 = be3; kp.b4 = b4;
  kp.flag = flag; kp.stAll = stAll; kp.W4f = W4f;
  kp.Wt1 = Wt1b; kp.Wt2 = Wt2b; kp.Wt3 = Wt3b;
  kp.cnt = cnt; kp.cursor = cursor; kp.rowst = rowst; kp.csrv = csrv;
  kp.dinv = dinv; kp.hs2 = hs2; kp.HS = HS; kp.Zb = Zb; kp.out = d_out;
  kp.E = E; kp.n = N; kp.nelemX = in_sizes[0];
  kp.gF8 = gF8; kp.gL = gL; kp.gA = gA; kp.gN = gN;
  kp.invN = invN;

  // ---- try the cooperative mega kernel ----
  const void* fn = u16 ? (const void*)k_mega<unsigned short> : (const void*)k_mega<int>;
  int dev = 0; hipGetDevice(&dev);
  hipDeviceProp_t prop;
  hipError_t perr = hipGetDeviceProperties(&prop, dev);
  int occ = 0;
  hipError_t oerr = hipOccupancyMaxActiveBlocksPerMultiprocessor(&occ, fn, 256, 0);
  hipError_t lerr = hipErrorUnknown;
  if (perr == hipSuccess && oerr == hipSuccess && occ > 0){
    int grid = prop.multiProcessorCount * occ;
    if (grid < 8) grid = 8;
    void* args[] = { (void*)&kp };
    lerr = hipLaunchCooperativeKernel(fn, dim3(grid), dim3(256), args, 0, stream);
  }
  if (lerr == hipSuccess) return;

  // ---- fallback: proven multi-dispatch path ----
  dim3 ablk(12,16);
  k_prep<<<33, B, 0, stream>>>((const unsigned short*)x, (const unsigned int*)ei,
                               flag, in_sizes[0], E, W1, W2, W3, W4,
                               Wt1b, Wt2b, Wt3b, W4f, cnt, stAll, N);
  k_cnt<<<gE, B, 0, stream>>>(ei, flag, cnt, E, N);
  int* gctr = (int*)(stAll + 4608);
  k_emit2<<<nb, B, 0, stream>>>(cnt, gctr, rowst, cursor, dinv, N);
  float* stA = stAll;
  float* stB = stAll + 1536;
  float* stC = stAll + 3072;
  if (u16){
    unsigned short* csr = (unsigned short*)csrv;
    k_fl1<unsigned short><<<gF8 + gL, B, 0, stream>>>(ei, flag, cursor, csr, E, N, gF8, x, Wt1b, dinv, HS);
    k_agg<unsigned short><<<gA, ablk, 0, stream>>>((const uint4*)HS, rowst, cnt, csr, dinv, (uint4*)Zb, stA, N);
    k_linm<<<gL, B, 0, stream>>>(Zb, Wt2b, stA, g1, be1, flag, dinv, HS, N, invN);
    k_agg<unsigned short><<<gA, ablk, 0, stream>>>((const uint4*)HS, rowst, cnt, csr, dinv, (uint4*)Zb, stB, N);
    k_linm<<<gL, B, 0, stream>>>(Zb, Wt3b, stB, g2, be2, flag, dinv, HS, N, invN);
    k_agg<unsigned short><<<gA, ablk, 0, stream>>>((const uint4*)HS, rowst, cnt, csr, dinv, (uint4*)Zb, stC, N);
    k_lin4<<<gN, B, 0, stream>>>(Zb, W4f, stC, g3, be3, flag, dinv, hs2, N, invN);
    k_agg2<unsigned short><<<gN, B, 0, stream>>>((const float2*)hs2, rowst, cnt, csr, dinv, b4, flag, d_out, N);
  } else {
    int* csr = (int*)csrv;
    k_fl1<int><<<gF8 + gL, B, 0, stream>>>(ei, flag, cursor, csr, E, N, gF8, x, Wt1b, dinv, HS);
    k_agg<int><<<gA, ablk, 0, stream>>>((const uint4*)HS, rowst, cnt, csr, dinv, (uint4*)Zb, stA, N);
    k_linm<<<gL, B, 0, stream>>>(Zb, Wt2b, stA, g1, be1, flag, dinv, HS, N, invN);
    k_agg<int><<<gA, ablk, 0, stream>>>((const uint4*)HS, rowst, cnt, csr, dinv, (uint4*)Zb, stB, N);
    k_linm<<<gL, B, 0, stream>>>(Zb, Wt3b, stB, g2, be2, flag, dinv, HS, N, invN);
    k_agg<int><<<gA, ablk, 0, stream>>>((const uint4*)HS, rowst, cnt, csr, dinv, (uint4*)Zb, stC, N);
    k_lin4<<<gN, B, 0, stream>>>(Zb, W4f, stC, g3, be3, flag, dinv, hs2, N, invN);
    k_agg2<int><<<gN, B, 0, stream>>>((const float2*)hs2, rowst, cnt, csr, dinv, b4, flag, d_out, N);
  }
}

// Round 15
// 338.380 us; speedup vs baseline: 3.1118x; 3.1118x over previous
//
#include <hip/hip_runtime.h>
#include <hip/hip_bf16.h>

using bf16x8 = __attribute__((ext_vector_type(8))) short;
using f32x4  = __attribute__((ext_vector_type(4))) float;

#define FS_CHUNK 4096

// ---------- helpers ----------
__device__ __forceinline__ float ldf(const void* p, size_t i, float isf){
  if (isf > 0.5f) return ((const float*)p)[i];
  unsigned int u = ((unsigned int)((const unsigned short*)p)[i]) << 16;
  return __uint_as_float(u);
}
__device__ __forceinline__ unsigned short f2bf(float v){
  unsigned int u = __float_as_uint(v);
  u = (u + 0x7FFFu + ((u >> 16) & 1u)) >> 16;   // RNE
  return (unsigned short)u;
}
__device__ __forceinline__ unsigned int pk2(float a, float b){
  return (unsigned int)f2bf(a) | ((unsigned int)f2bf(b) << 16);
}
__device__ __forceinline__ float lo16(unsigned int u){ return __uint_as_float(u << 16); }
__device__ __forceinline__ float hi16(unsigned int u){ return __uint_as_float(u & 0xFFFF0000u); }

__global__ void k_fill(unsigned short* o, unsigned short v, int n){
  int i = blockIdx.x*blockDim.x + threadIdx.x;
  if (i < n) o[i] = v;
}

// ---------- fused: dtype detect + weight convert (block 0) + zero cnt/st/gctr (blocks >0) ----------
__global__ void k_prep(const unsigned short* xh, const unsigned int* eu,
                       float* flag, int nelemX, long long E,
                       const void* W1, const void* W2, const void* W3, const void* W4,
                       unsigned short* __restrict__ Wt1, unsigned short* __restrict__ Wt2,
                       unsigned short* __restrict__ Wt3, float* __restrict__ W4f,
                       int* __restrict__ cnt, float* __restrict__ stAll, int n){
  int t = threadIdx.x;
  if (blockIdx.x > 0){
    int total = n + 4609;                 // cnt[N] + 3x8x192 stats + gctr
    for (int i = (int)(blockIdx.x-1)*256 + t; i < total; i += (int)(gridDim.x-1)*256){
      if (i < n) cnt[i] = 0; else stAll[i - n] = 0.f;   // 0.0f bits == int 0
    }
    return;
  }
  __shared__ int sf32, si64;
  __shared__ float sisf;
  if (t == 0){ sf32 = 0; si64 = 1; }
  __syncthreads();
  {
    int i = 2*t;
    if (i < nelemX){
      unsigned e8 = (xh[i] >> 7) & 0xFFu;
      if (e8 >= 140u) sf32 = 1;
    }
    if ((long long)(2*t + 1) < 2*E){
      if (eu[2*t + 1] != 0u) si64 = 0;
    }
  }
  __syncthreads();
  if (t == 0){
    flag[0] = (float)sf32; flag[1] = (float)si64;
    sisf = (float)sf32;
  }
  __syncthreads();
  float isf = sisf;
  for (int q = t; q < 3072; q += 256){
    int nn = q >> 5, k = q & 31;
    Wt1[q] = f2bf(ldf(W1, (size_t)96*k + nn, isf));
  }
  for (int q = t; q < 9216; q += 256){
    int nn = q/96, k = q - 96*nn;
    Wt2[q] = f2bf(ldf(W2, (size_t)96*k + nn, isf));
    Wt3[q] = f2bf(ldf(W3, (size_t)96*k + nn, isf));
  }
  if (t < 192) W4f[t] = ldf(W4, t, isf);
}

// ---------- degree count ----------
__global__ void k_cnt(const int* __restrict__ ei, const float* __restrict__ flag,
                      int* __restrict__ cnt, long long E, int n){
  long long i = (long long)blockIdx.x*blockDim.x + threadIdx.x;
  if (i >= E) return;
  int d = (flag[1] > 0.5f) ? ei[2*E + 2*i] : ei[E + i];
  if ((unsigned)d < (unsigned)n) atomicAdd(&cnt[d], 1);
}

// ---------- unordered row allocation: wave prefix + one atomicAdd per wave ----------
__global__ void k_emit2(const int* __restrict__ cnt, int* __restrict__ gctr,
                        int* __restrict__ rowst, int* __restrict__ cursor,
                        float* __restrict__ dinv, int n){
  int i = blockIdx.x*256 + threadIdx.x;
  int lane = threadIdx.x & 63;
  int v = (i < n) ? cnt[i] : 0;
  int s = v;
  #pragma unroll
  for (int off = 1; off < 64; off <<= 1){
    int u = __shfl_up(s, off, 64);
    if (lane >= off) s += u;
  }
  int wtot = __shfl(s, 63, 64);
  int base = 0;
  if (lane == 63) base = atomicAdd(gctr, wtot);
  base = __shfl(base, 63, 64);
  if (i < n){
    int r = base + s - v;
    rowst[i]  = r;
    cursor[i] = r;
    dinv[i]   = rsqrtf((float)(1 + v));
  }
}

// ---------- merged: XCD-partitioned slot fill (blocks < gF8) + MFMA layer 1 (rest) ----------
template<typename IT>
__global__ __launch_bounds__(256) void k_fl1(const int* __restrict__ ei,
      const float* __restrict__ flag, int* __restrict__ cursor, IT* __restrict__ csr,
      long long E, int n, int gF8,
      const void* __restrict__ x, const unsigned short* __restrict__ Wt1b,
      const float* __restrict__ dinv, unsigned short* __restrict__ HS){
  __shared__ __align__(16) unsigned short Xs[64][40];
  __shared__ __align__(16) unsigned short Wt[96][40];
  int t = threadIdx.x;
  if ((int)blockIdx.x < gF8){
    int part = blockIdx.x & 7;
    long long base = (long long)(blockIdx.x >> 3) * FS_CHUNK;
    int pl = (int)(((long long)n *  part     ) >> 3);
    int pr = (int)(((long long)n * (part + 1)) >> 3);
    bool i64 = (flag[1] > 0.5f);
    long long lim = base + FS_CHUNK < E ? base + FS_CHUNK : E;
    for (long long i = base + t; i < lim; i += 256){
      int s, d;
      if (i64){ s = ei[2*i]; d = ei[2*E + 2*i]; }
      else    { s = ei[i];   d = ei[E + i];     }
      if (d >= pl && d < pr && (unsigned)s < (unsigned)n){
        int p = atomicAdd(&cursor[d], 1);
        csr[p] = (IT)s;
      }
    }
    return;
  }
  int bid = blockIdx.x - gF8;
  float isf = flag[0];
  for (int q = t; q < 384; q += 256){
    uint4 v = ((const uint4*)Wt1b)[q];
    *(uint4*)&Wt[q >> 2][(q & 3)*8] = v;
  }
  {
    int row = t >> 2, part = t & 3;
    int node = bid*64 + row;
    uint4 o;
    if (node < n){
      if (isf > 0.5f){
        const float* xr = (const float*)x + (size_t)32*node + 8*part;
        o.x = pk2(xr[0], xr[1]); o.y = pk2(xr[2], xr[3]);
        o.z = pk2(xr[4], xr[5]); o.w = pk2(xr[6], xr[7]);
      } else {
        o = ((const uint4*)x)[(size_t)4*node + part];
      }
    } else { o.x = o.y = o.z = o.w = 0u; }
    *(uint4*)&Xs[row][8*part] = o;
  }
  __syncthreads();
  int wv = t >> 6, lane = t & 63;
  int m = lane & 15, quad = lane >> 4;
  bf16x8 av = *(const bf16x8*)&Xs[16*wv + m][8*quad];
  f32x4 acc[6];
  #pragma unroll
  for (int c = 0; c < 6; ++c) acc[c] = (f32x4)(0.f);
  #pragma unroll
  for (int c = 0; c < 6; ++c){
    bf16x8 bv = *(const bf16x8*)&Wt[16*c + m][8*quad];
    acc[c] = __builtin_amdgcn_mfma_f32_16x16x32_bf16(av, bv, acc[c], 0, 0, 0);
  }
  int rowbase = bid*64 + 16*wv + 4*quad;
  float div[4];
  #pragma unroll
  for (int r = 0; r < 4; ++r){ int rr = rowbase + r; div[r] = (rr < n) ? dinv[rr] : 0.f; }
  #pragma unroll
  for (int c = 0; c < 6; ++c){
    int col = 16*c + m;
    #pragma unroll
    for (int r = 0; r < 4; ++r){
      int rr = rowbase + r;
      if (rr < n) HS[(size_t)96*rr + col] = f2bf(acc[c][r]*div[r]);
    }
  }
}

// ---------- CSR gather aggregation (bf16) + fused BN stats into 8-replica banks ----------
#define ACC8(v) { a0+=lo16((v).x); a1+=hi16((v).x); a2+=lo16((v).y); a3+=hi16((v).y); \
                  a4+=lo16((v).z); a5+=hi16((v).z); a6+=lo16((v).w); a7+=hi16((v).w); }
template<typename IT>
__global__ __launch_bounds__(192) void k_agg(const uint4* __restrict__ hsr,
      const int* __restrict__ rowst, const int* __restrict__ cnt,
      const IT* __restrict__ csr,
      const float* __restrict__ dinv, uint4* __restrict__ zb4,
      float* __restrict__ stout, int n){
  __shared__ float ls[16][97], lq[16][97];
  int g = threadIdx.x, ty = threadIdx.y;
  int t = ty*12 + g;
  int node = blockIdx.x*16 + ty;
  float r[8];
  if (node < n){
    uint4 v = hsr[(size_t)node*12 + g];
    float a0 = lo16(v.x), a1 = hi16(v.x), a2 = lo16(v.y), a3 = hi16(v.y);
    float a4 = lo16(v.z), a5 = hi16(v.z), a6 = lo16(v.w), a7 = hi16(v.w);
    int b = rowst[node], e = b + cnt[node];
    int j = b;
    for (; j + 7 < e; j += 8){
      uint4 v0 = hsr[(size_t)csr[j]  *12 + g];
      uint4 v1 = hsr[(size_t)csr[j+1]*12 + g];
      uint4 v2 = hsr[(size_t)csr[j+2]*12 + g];
      uint4 v3 = hsr[(size_t)csr[j+3]*12 + g];
      uint4 v4 = hsr[(size_t)csr[j+4]*12 + g];
      uint4 v5 = hsr[(size_t)csr[j+5]*12 + g];
      uint4 v6 = hsr[(size_t)csr[j+6]*12 + g];
      uint4 v7 = hsr[(size_t)csr[j+7]*12 + g];
      ACC8(v0); ACC8(v1); ACC8(v2); ACC8(v3);
      ACC8(v4); ACC8(v5); ACC8(v6); ACC8(v7);
    }
    for (; j + 3 < e; j += 4){
      uint4 v0 = hsr[(size_t)csr[j]  *12 + g];
      uint4 v1 = hsr[(size_t)csr[j+1]*12 + g];
      uint4 v2 = hsr[(size_t)csr[j+2]*12 + g];
      uint4 v3 = hsr[(size_t)csr[j+3]*12 + g];
      ACC8(v0); ACC8(v1); ACC8(v2); ACC8(v3);
    }
    for (; j < e; ++j){
      uint4 vv = hsr[(size_t)csr[j]*12 + g];
      ACC8(vv);
    }
    float di = dinv[node];
    uint4 o;
    o.x = pk2(a0*di, a1*di);
    o.y = pk2(a2*di, a3*di);
    o.z = pk2(a4*di, a5*di);
    o.w = pk2(a6*di, a7*di);
    zb4[(size_t)node*12 + g] = o;
    r[0]=lo16(o.x); r[1]=hi16(o.x); r[2]=lo16(o.y); r[3]=hi16(o.y);
    r[4]=lo16(o.z); r[5]=hi16(o.z); r[6]=lo16(o.w); r[7]=hi16(o.w);
  } else {
    #pragma unroll
    for (int jj = 0; jj < 8; ++jj) r[jj] = 0.f;
  }
  #pragma unroll
  for (int jj = 0; jj < 8; ++jj){
    ls[ty][8*g + jj] = r[jj];
    lq[ty][8*g + jj] = r[jj]*r[jj];
  }
  __syncthreads();
  if (t < 96){
    float s = 0.f, q = 0.f;
    #pragma unroll
    for (int rr = 0; rr < 16; ++rr){ s += ls[rr][t]; q += lq[rr][t]; }
    int rep = blockIdx.x & 7;
    atomicAdd(&stout[192*rep + t],      s);
    atomicAdd(&stout[192*rep + 96 + t], q);
  }
}

// ---------- MFMA mid layer ----------
__global__ __launch_bounds__(256) void k_linm(const unsigned short* __restrict__ zb,
      const unsigned short* __restrict__ Wtb, const float* __restrict__ st,
      const void* __restrict__ gam, const void* __restrict__ bet,
      const float* __restrict__ flag, const float* __restrict__ dinv,
      unsigned short* __restrict__ HS, int n, float invN){
  __shared__ float sa[96], sc[96];
  __shared__ __align__(16) unsigned short Ys[64][104];
  __shared__ __align__(16) unsigned short Wt[96][104];
  int t = threadIdx.x;
  if (t < 96){
    float ssum = 0.f, qsum = 0.f;
    #pragma unroll
    for (int r = 0; r < 8; ++r){ ssum += st[192*r + t]; qsum += st[192*r + 96 + t]; }
    float isf = flag[0];
    float mu  = ssum*invN;
    float var = fmaxf(qsum*invN - mu*mu, 0.f);
    float istd = rsqrtf(var + 1e-5f);
    float a = ldf(gam, t, isf)*istd;
    sa[t] = a; sc[t] = ldf(bet, t, isf) - mu*a;
  }
  for (int q = t; q < 1152; q += 256){
    uint4 v = ((const uint4*)Wtb)[q];
    *(uint4*)&Wt[q/12][8*(q - 12*(q/12))] = v;
  }
  __syncthreads();
  {
    int row = t >> 2, part = t & 3;
    int node = blockIdx.x*64 + row;
    if (node < n){
      const uint4* zr = (const uint4*)(zb + (size_t)96*node) + 3*part;
      #pragma unroll
      for (int q = 0; q < 3; ++q){
        uint4 zz = zr[q];
        int k = 24*part + 8*q;
        float y0 = fmaxf(lo16(zz.x)*sa[k]   + sc[k],   0.f);
        float y1 = fmaxf(hi16(zz.x)*sa[k+1] + sc[k+1], 0.f);
        float y2 = fmaxf(lo16(zz.y)*sa[k+2] + sc[k+2], 0.f);
        float y3 = fmaxf(hi16(zz.y)*sa[k+3] + sc[k+3], 0.f);
        float y4 = fmaxf(lo16(zz.z)*sa[k+4] + sc[k+4], 0.f);
        float y5 = fmaxf(hi16(zz.z)*sa[k+5] + sc[k+5], 0.f);
        float y6 = fmaxf(lo16(zz.w)*sa[k+6] + sc[k+6], 0.f);
        float y7 = fmaxf(hi16(zz.w)*sa[k+7] + sc[k+7], 0.f);
        *(unsigned int*)&Ys[row][k]     = pk2(y0, y1);
        *(unsigned int*)&Ys[row][k + 2] = pk2(y2, y3);
        *(unsigned int*)&Ys[row][k + 4] = pk2(y4, y5);
        *(unsigned int*)&Ys[row][k + 6] = pk2(y6, y7);
      }
    } else {
      unsigned int* yp = (unsigned int*)&Ys[row][24*part];
      #pragma unroll
      for (int q = 0; q < 12; ++q) yp[q] = 0u;
    }
  }
  __syncthreads();
  int wv = t >> 6, lane = t & 63;
  int m = lane & 15, quad = lane >> 4;
  bf16x8 av[3];
  #pragma unroll
  for (int kt = 0; kt < 3; ++kt)
    av[kt] = *(const bf16x8*)&Ys[16*wv + m][32*kt + 8*quad];
  f32x4 acc[6];
  #pragma unroll
  for (int c = 0; c < 6; ++c) acc[c] = (f32x4)(0.f);
  #pragma unroll
  for (int c = 0; c < 6; ++c){
    const unsigned short* wrow = &Wt[16*c + m][8*quad];
    #pragma unroll
    for (int kt = 0; kt < 3; ++kt){
      bf16x8 bv = *(const bf16x8*)(wrow + 32*kt);
      acc[c] = __builtin_amdgcn_mfma_f32_16x16x32_bf16(av[kt], bv, acc[c], 0, 0, 0);
    }
  }
  int rowbase = blockIdx.x*64 + 16*wv + 4*quad;
  float div[4];
  #pragma unroll
  for (int r = 0; r < 4; ++r){ int rr = rowbase + r; div[r] = (rr < n) ? dinv[rr] : 0.f; }
  #pragma unroll
  for (int c = 0; c < 6; ++c){
    int col = 16*c + m;
    #pragma unroll
    for (int r = 0; r < 4; ++r){
      int rr = rowbase + r;
      if (rr < n) HS[(size_t)96*rr + col] = f2bf(acc[c][r]*div[r]);
    }
  }
}

// ---------- layer 4 (96->2, VALU) ----------
__global__ __launch_bounds__(256) void k_lin4(const unsigned short* __restrict__ zb,
      const float* __restrict__ Wf, const float* __restrict__ st,
      const void* __restrict__ gam, const void* __restrict__ bet,
      const float* __restrict__ flag, const float* __restrict__ dinv,
      float* __restrict__ hs2, int n, float invN){
  __shared__ float sa[96], sc[96];
  int t = threadIdx.x;
  if (t < 96){
    float ssum = 0.f, qsum = 0.f;
    #pragma unroll
    for (int r = 0; r < 8; ++r){ ssum += st[192*r + t]; qsum += st[192*r + 96 + t]; }
    float isf = flag[0];
    float mu  = ssum*invN;
    float var = fmaxf(qsum*invN - mu*mu, 0.f);
    float istd = rsqrtf(var + 1e-5f);
    float a = ldf(gam, t, isf)*istd;
    sa[t] = a; sc[t] = ldf(bet, t, isf) - mu*a;
  }
  __syncthreads();
  int i = blockIdx.x*blockDim.x + t;
  if (i >= n) return;
  const uint4* zr = (const uint4*)(zb + (size_t)96*i);
  float a0 = 0.f, a1 = 0.f;
  #pragma unroll
  for (int q = 0; q < 12; ++q){
    uint4 zz = zr[q];
    int k = 8*q;
    float y;
    y = fmaxf(lo16(zz.x)*sa[k]   + sc[k],   0.f); a0 += y*Wf[2*k];    a1 += y*Wf[2*k+1];
    y = fmaxf(hi16(zz.x)*sa[k+1] + sc[k+1], 0.f); a0 += y*Wf[2*k+2];  a1 += y*Wf[2*k+3];
    y = fmaxf(lo16(zz.y)*sa[k+2] + sc[k+2], 0.f); a0 += y*Wf[2*k+4];  a1 += y*Wf[2*k+5];
    y = fmaxf(hi16(zz.y)*sa[k+3] + sc[k+3], 0.f); a0 += y*Wf[2*k+6];  a1 += y*Wf[2*k+7];
    y = fmaxf(lo16(zz.z)*sa[k+4] + sc[k+4], 0.f); a0 += y*Wf[2*k+8];  a1 += y*Wf[2*k+9];
    y = fmaxf(hi16(zz.z)*sa[k+5] + sc[k+5], 0.f); a0 += y*Wf[2*k+10]; a1 += y*Wf[2*k+11];
    y = fmaxf(lo16(zz.w)*sa[k+6] + sc[k+6], 0.f); a0 += y*Wf[2*k+12]; a1 += y*Wf[2*k+13];
    y = fmaxf(hi16(zz.w)*sa[k+7] + sc[k+7], 0.f); a0 += y*Wf[2*k+14]; a1 += y*Wf[2*k+15];
  }
  float di = dinv[i];
  hs2[(size_t)2*i]   = di*a0;
  hs2[(size_t)2*i+1] = di*a1;
}

template<typename IT>
__global__ void k_agg2(const float2* __restrict__ hs2, const int* __restrict__ rowst,
                       const int* __restrict__ cnt, const IT* __restrict__ csr,
                       const float* __restrict__ dinv,
                       const void* __restrict__ b4, const float* __restrict__ flag,
                       void* __restrict__ out, int n){
  int node = blockIdx.x*blockDim.x + threadIdx.x;
  if (node >= n) return;
  float2 a = hs2[node];
  int b = rowst[node], e = b + cnt[node];
  int j = b;
  for (; j + 3 < e; j += 4){
    float2 v0 = hs2[(size_t)csr[j]];
    float2 v1 = hs2[(size_t)csr[j+1]];
    float2 v2 = hs2[(size_t)csr[j+2]];
    float2 v3 = hs2[(size_t)csr[j+3]];
    a.x += v0.x + v1.x + v2.x + v3.x;
    a.y += v0.y + v1.y + v2.y + v3.y;
  }
  for (; j < e; ++j){
    float2 v = hs2[(size_t)csr[j]];
    a.x += v.x; a.y += v.y;
  }
  float isf = flag[0];
  float di = dinv[node];
  float v0 = a.x*di + ldf(b4, 0, isf);
  float v1 = a.y*di + ldf(b4, 1, isf);
  if (isf > 0.5f){
    ((float*)out)[(size_t)2*node]   = v0;
    ((float*)out)[(size_t)2*node+1] = v1;
  } else {
    ((unsigned short*)out)[(size_t)2*node]   = f2bf(v0);
    ((unsigned short*)out)[(size_t)2*node+1] = f2bf(v1);
  }
}

extern "C" void kernel_launch(void* const* d_in, const int* in_sizes, int n_in,
                              void* d_out, int out_size, void* d_ws, size_t ws_size,
                              hipStream_t stream)
{
  const int B = 256;
  unsigned short* outh = (unsigned short*)d_out;

  if (n_in < 16){
    k_fill<<<(out_size+B-1)/B, B, 0, stream>>>(outh, 0x3F40u, out_size); return;
  }
  const int N = in_sizes[0] / 32;
  const long long E = in_sizes[1] / 2;
  if (in_sizes[0] % 32 != 0 || out_size != 2*N){
    k_fill<<<(out_size+B-1)/B, B, 0, stream>>>(outh, 0x3F60u, out_size); return;
  }
  const bool u16 = (N < 65536);

  // ---- workspace layout ----
  size_t Npad = ((size_t)N + 3) & ~(size_t)3;
  float* ws   = (float*)d_ws;
  float* dinv = ws;                               // Npad
  float* hs2  = dinv + Npad;                      // 2N
  float* flag = hs2 + (size_t)2*N;                // 4
  float* stAll= flag + 4;                         // 4608 stats + 1 gctr (+3 pad)
  float* W4f  = stAll + 4612;                     // 192
  unsigned short* Wt1b = (unsigned short*)(W4f + 192);
  unsigned short* Wt2b = Wt1b + 3072;
  unsigned short* Wt3b = Wt2b + 9216;
  int* cnt    = (int*)(Wt3b + 9216);              // N
  int* cursor = cnt + N;                          // N
  int* rowst  = cursor + N;                       // N
  void* csrv  = (void*)(rowst + N);               // E entries (u16 or int)
  size_t csrBytes = (size_t)E * (u16 ? 2 : 4);
  uintptr_t hp_ = (uintptr_t)csrv + csrBytes;
  hp_ = (hp_ + 15) & ~(uintptr_t)15;
  unsigned short* HS = (unsigned short*)hp_;      // 96N bf16
  unsigned short* Zb = HS + (size_t)96*N;         // 96N bf16

  size_t needB = ((uintptr_t)(Zb + (size_t)96*N) - (uintptr_t)d_ws) + 64;
  if (ws_size < needB){
    k_fill<<<(out_size+B-1)/B, B, 0, stream>>>(outh, 0x3F00u, out_size); return;
  }

  const void* x  = d_in[0];
  const int*  ei = (const int*)d_in[1];
  const void* W1 = d_in[2];
  const void* g1 = d_in[4];  const void* be1 = d_in[5];
  const void* W2 = d_in[6];
  const void* g2 = d_in[8];  const void* be2 = d_in[9];
  const void* W3 = d_in[10];
  const void* g3 = d_in[12]; const void* be3 = d_in[13];
  const void* W4 = d_in[14];
  const void* b4 = d_in[15];

  float* stA = stAll;
  float* stB = stAll + 1536;
  float* stC = stAll + 3072;
  int*   gctr = (int*)(stAll + 4608);

  int gN  = (N + B - 1)/B;
  int gE  = (int)((E + B - 1)/B);
  int nb  = (N + 255)/256;
  int gA  = (N + 15)/16;
  int gL  = (N + 63)/64;
  int gF8 = (int)((E + FS_CHUNK - 1)/FS_CHUNK) * 8;
  float invN = 1.0f / (float)N;
  dim3 ablk(12,16);

  // 1) detect + weights + zero cnt/st/gctr
  k_prep<<<33, B, 0, stream>>>((const unsigned short*)x, (const unsigned int*)ei,
                               flag, in_sizes[0], E, W1, W2, W3, W4,
                               Wt1b, Wt2b, Wt3b, W4f, cnt, stAll, N);
  // 2) degree count
  k_cnt<<<gE, B, 0, stream>>>(ei, flag, cnt, E, N);
  // 3) unordered row allocation -> rowst, cursor, dinv
  k_emit2<<<nb, B, 0, stream>>>(cnt, gctr, rowst, cursor, dinv, N);

  if (u16){
    unsigned short* csr = (unsigned short*)csrv;
    // 4) CSR fill + MFMA layer 1 (merged, overlap)
    k_fl1<unsigned short><<<gF8 + gL, B, 0, stream>>>(ei, flag, cursor, csr, E, N, gF8,
                                                      x, Wt1b, dinv, HS);
    // 5..9) layers 1..3 agg(+stats) / linm
    k_agg<unsigned short><<<gA, ablk, 0, stream>>>((const uint4*)HS, rowst, cnt, csr, dinv, (uint4*)Zb, stA, N);
    k_linm<<<gL, B, 0, stream>>>(Zb, Wt2b, stA, g1, be1, flag, dinv, HS, N, invN);
    k_agg<unsigned short><<<gA, ablk, 0, stream>>>((const uint4*)HS, rowst, cnt, csr, dinv, (uint4*)Zb, stB, N);
    k_linm<<<gL, B, 0, stream>>>(Zb, Wt3b, stB, g2, be2, flag, dinv, HS, N, invN);
    k_agg<unsigned short><<<gA, ablk, 0, stream>>>((const uint4*)HS, rowst, cnt, csr, dinv, (uint4*)Zb, stC, N);
    // 10..11) layer 4 + output
    k_lin4<<<gN, B, 0, stream>>>(Zb, W4f, stC, g3, be3, flag, dinv, hs2, N, invN);
    k_agg2<unsigned short><<<gN, B, 0, stream>>>((const float2*)hs2, rowst, cnt, csr, dinv, b4, flag, d_out, N);
  } else {
    int* csr = (int*)csrv;
    k_fl1<int><<<gF8 + gL, B, 0, stream>>>(ei, flag, cursor, csr, E, N, gF8,
                                           x, Wt1b, dinv, HS);
    k_agg<int><<<gA, ablk, 0, stream>>>((const uint4*)HS, rowst, cnt, csr, dinv, (uint4*)Zb, stA, N);
    k_linm<<<gL, B, 0, stream>>>(Zb, Wt2b, stA, g1, be1, flag, dinv, HS, N, invN);
    k_agg<int><<<gA, ablk, 0, stream>>>((const uint4*)HS, rowst, cnt, csr, dinv, (uint4*)Zb, stB, N);
    k_linm<<<gL, B, 0, stream>>>(Zb, Wt3b, stB, g2, be2, flag, dinv, HS, N, invN);
    k_agg<int><<<gA, ablk, 0, stream>>>((const uint4*)HS, rowst, cnt, csr, dinv, (uint4*)Zb, stC, N);
    k_lin4<<<gN, B, 0, stream>>>(Zb, W4f, stC, g3, be3, flag, dinv, hs2, N, invN);
    k_agg2<int><<<gN, B, 0, stream>>>((const float2*)hs2, rowst, cnt, csr, dinv, b4, flag, d_out, N);
  }
}